// Round 4
// baseline (506.102 us; speedup 1.0000x reference)
//
#include <hip/hip_runtime.h>

// CTC forward loss, linear-space (scaled) forward algorithm, fp64 alpha.
// B=256, T=1024, C=256 (blank=255), L=128, S=2L+1=257.
// One 64-lane wave per batch element; lane l holds states 4l+1..4l+4 (fp64)
// plus replicated state 0. Neighbors via DPP WAVE_SHR1 (no barriers).
//
// Pipeline: coalesced dwordx4 row loads -> rbuf (VGPR, depth 8) ->
// ds_write_b128 ring (8 x 1KB LDS slots) -> ds_read_b32 per-class gather
// (2 random + 1 broadcast) 2 steps ahead of compute. Waits are pure
// register-dependency (fine-grained vmcnt/lgkmcnt); no barriers.
//
// Round-3 post-mortem: tail reloaded rbuf with row 1023 unconditionally,
// but rows 1020..1022 still transit rbuf->LDS during the tail (row r is
// written at iter r-3 from a slot reloaded at iter r-11). Frames 1020-1022
// got frame-1023 data -> absmax 7.0. Fix: tail uses the same clamped
// reload index as the main loop.

#define T_DIM 1024
#define C_DIM 256
#define L_DIM 128
#define EPSF  1e-7f
#define LN2D  0.69314718055994530942
#define DG    8   // gload -> ds_write pipeline depth (global latency cover)
#define DL    3   // ds_write happens DL steps ahead of compute
#define DS    2   // ds_read  happens DS steps ahead of compute
#define NS    8   // LDS ring slots (1 KB each)

// shuffle-up-by-1 across the 64-lane wave (both halves); lane 0 gets `old`.
__device__ __forceinline__ double dpp_shr1_f64(double old, double v) {
    int rlo = __builtin_amdgcn_update_dpp(__double2loint(old), __double2loint(v),
                                          0x138 /*WAVE_SHR1*/, 0xF, 0xF, false);
    int rhi = __builtin_amdgcn_update_dpp(__double2hiint(old), __double2hiint(v),
                                          0x138 /*WAVE_SHR1*/, 0xF, 0xF, false);
    return __hiloint2double(rhi, rlo);
}

// wave-wide int max (inputs >= 0), result broadcast via readlane(63).
__device__ __forceinline__ int wave_imax_all(int v) {
#define STAGE(CTRL) { int t_ = __builtin_amdgcn_update_dpp(v, v, CTRL, 0xF, 0xF, false); \
                      v = v > t_ ? v : t_; }
    STAGE(0x111)  // row_shr:1
    STAGE(0x112)  // row_shr:2
    STAGE(0x114)  // row_shr:4
    STAGE(0x118)  // row_shr:8
    STAGE(0x142)  // row_bcast:15
    STAGE(0x143)  // row_bcast:31
#undef STAGE
    return __builtin_amdgcn_readlane(v, 63);
}

__device__ __forceinline__ void ctc_step(double p0, double p1, double pB,
                                         double k1, double k3, double& a0,
                                         double& r1, double& r2, double& r3, double& r4) {
    // neighbors from previous lane: A[4l] = prev.r4, A[4l-1] = prev.r3
    double sA4 = dpp_shr1_f64(a0,  r4);   // lane0 <- state 0 (a0)
    double sA3 = dpp_shr1_f64(0.0, r3);   // lane0 <- 0 (state -1)
    double n1 = p0 * fma(k1, sA3, r1 + sA4);  // odd state 4l+1 (label 2l)
    double n2 = pB * (r2 + r1);               // blank state 4l+2
    double n3 = p1 * fma(k3, r1, r3 + r2);    // odd state 4l+3 (label 2l+1)
    double n4 = pB * (r4 + r3);               // blank state 4l+4
    a0 *= pB;                                 // state 0: blank self-loop only
    r1 = n1; r2 = n2; r3 = n3; r4 = n4;
}

__global__ __launch_bounds__(64, 1)
void ctc_fwd(const int* __restrict__ labels, const float* __restrict__ ypred,
             float* __restrict__ out) {
    const int b = blockIdx.x;
    const int l = threadIdx.x;  // lane 0..63
    const float* Yb = ypred + (size_t)b * (T_DIM * C_DIM);

    __shared__ float smem[NS * C_DIM];  // 8 KB row ring

    // labels 2l, 2l+1 (L=128 = exactly 2 per lane)
    const int2 lab = ((const int2*)(labels + b * L_DIM))[l];
    const int c0 = lab.x, c1 = lab.y;
    int cB;  // blank idx in a VGPR (keep init load on vmem path, not SMEM)
    asm("v_mov_b32 %0, 255" : "=v"(cB));

    const int labprev = __shfl_up(c1, 1, 64);
    const double k1 = (l == 0 || labprev == c0) ? 0.0 : 1.0;  // skip into 4l+1
    const double k3 = (c1 == c0) ? 0.0 : 1.0;                 // skip into 4l+3

    // t = 0 init: alpha0[0] = p'(0,blank), alpha0[1] = p'(0,label0)
    double a0 = (double)(Yb[cB] + EPSF);
    double r1 = (l == 0) ? (double)(Yb[c0] + EPSF) : 0.0;
    double r2 = 0.0, r3 = 0.0, r4 = 0.0;
    int e2acc = 0;

    // ---- pipeline state ----
    float4 rbuf[DG];            // row g lives in rbuf[g & 7] until ds_write
    float fr0[4], fr1[4], frB[4];  // scalar ring: row r in slot r & 3

    // prologue: rbuf <- rows 4..11 (what steady iters t<=0 would have loaded)
#pragma unroll
    for (int g = DL + 1; g <= DL + DG; ++g)
        rbuf[g & 7] = ((const float4*)(Yb + (size_t)g * C_DIM))[l];
    // LDS <- rows 1..3
#pragma unroll
    for (int w = 1; w <= DL; ++w) {
        float4 v = ((const float4*)(Yb + (size_t)w * C_DIM))[l];
        ((float4*)(smem + (w & 7) * C_DIM))[l] = v;
    }
    // scalar ring <- rows 1..2 (same-wave LDS ops are in-order: no barrier)
#pragma unroll
    for (int r = 1; r <= DS; ++r) {
        const float* row = smem + (r & 7) * C_DIM;
        fr0[r & 3] = row[c0]; fr1[r & 3] = row[c1]; frB[r & 3] = row[255];
    }

    // main loop: 63 chunks of 16 cover t = 1..1008 (tb = 1 mod 8 always ->
    // every ring index below is a compile-time constant after unrolling)
    for (int tb = 1; tb <= 993; tb += 16) {
#pragma unroll
        for (int d = 0; d < 16; ++d) {
            const int t = tb + d;
            // 1) ds_read scalars for row t+DS into ring slot (t+DS)&3
            {
                const float* row = smem + ((t + DS) & 7) * C_DIM;
                fr0[(t + DS) & 3] = row[c0];
                fr1[(t + DS) & 3] = row[c1];
                frB[(t + DS) & 3] = row[255];
            }
            // 2) ds_write row t+DL from rbuf, then 3) reload that rbuf slot
            {
                const int ws = (t + DL) & 7;
                ((float4*)(smem + ws * C_DIM))[l] = rbuf[ws];
                int g = t + DL + DG; g = g > T_DIM - 1 ? T_DIM - 1 : g;
                rbuf[ws] = ((const float4*)(Yb + (size_t)g * C_DIM))[l];
            }
            // 4) compute step t from ring slot t&3
            ctc_step((double)(fr0[t & 3] + EPSF), (double)(fr1[t & 3] + EPSF),
                     (double)(frB[t & 3] + EPSF), k1, k3, a0, r1, r2, r3, r4);
        }
        // rescale by exact power of two (exponent = int max of f64 hi words)
        int h = __double2hiint(r1);
        int t_;
        t_ = __double2hiint(r2); h = h > t_ ? h : t_;
        t_ = __double2hiint(r3); h = h > t_ ? h : t_;
        t_ = __double2hiint(r4); h = h > t_ ? h : t_;
        t_ = __double2hiint(a0); h = h > t_ ? h : t_;
        int H = wave_imax_all(h);
        int k = (H >> 20) - 1023;
        double s = __hiloint2double((1023 - k) << 20, 0);  // exact 2^-k
        r1 *= s; r2 *= s; r3 *= s; r4 *= s; a0 *= s;
        e2acc += k;
    }

    // tail: t = 1009..1023 — IDENTICAL body to the main loop (clamped rbuf
    // reload: t=1009..1011 still fetch rows 1020..1022; t>=1012 clamp to
    // 1023, whose dup writes land only in slots consumed as rows > 1023).
#pragma unroll
    for (int t = 1009; t <= 1023; ++t) {
        {
            const float* row = smem + ((t + DS) & 7) * C_DIM;
            fr0[(t + DS) & 3] = row[c0];
            fr1[(t + DS) & 3] = row[c1];
            frB[(t + DS) & 3] = row[255];
        }
        {
            const int ws = (t + DL) & 7;
            ((float4*)(smem + ws * C_DIM))[l] = rbuf[ws];
            int g = t + DL + DG; g = g > T_DIM - 1 ? T_DIM - 1 : g;
            rbuf[ws] = ((const float4*)(Yb + (size_t)g * C_DIM))[l];
        }
        ctc_step((double)(fr0[t & 3] + EPSF), (double)(fr1[t & 3] + EPSF),
                 (double)(frB[t & 3] + EPSF), k1, k3, a0, r1, r2, r3, r4);
    }

    // loss = -( ln(A[255]+A[256]) + ln2 * e2acc ); states 255,256 = lane63 r3,r4
    if (l == 63) {
        double sum = r3 + r4;
        int hi = __double2hiint(sum), lo = __double2loint(sum);
        int e = (hi >> 20) - 1023;
        double mant = __hiloint2double((hi & 0x000FFFFF) | (1023 << 20), lo);
        double lg2 = (double)__log2f((float)mant) + (double)(e + e2acc);
        out[b] = (float)(-LN2D * lg2);
    }
}

extern "C" void kernel_launch(void* const* d_in, const int* in_sizes, int n_in,
                              void* d_out, int out_size, void* d_ws, size_t ws_size,
                              hipStream_t stream) {
    const int* y_true = (const int*)d_in[0];     // [256,128] int32
    const float* y_pred = (const float*)d_in[1]; // [256,1024,256] fp32
    float* out = (float*)d_out;                  // [256,1] fp32
    ctc_fwd<<<256, 64, 0, stream>>>(y_true, y_pred, out);
}